// Round 3
// baseline (339.606 us; speedup 1.0000x reference)
//
#include <hip/hip_runtime.h>
#include <hip/hip_bf16.h>
#include <math.h>

// Cosine attention, n=8, L=S=2048, d=v=64.
// out0 = softmax((q^·k^T)/8) @ V  [8,2048,64]; out1 = softmax scores [8,2048,2048]
// |score| <= 1/8 (unit vectors) -> exp in [0.88,1.13] -> no max subtraction.
// Normalization linear -> PV runs on unnormalized exp, scaled at the end.
// Mask arrives as int32. R2 analysis: latency-bound on per-iter mask loads ->
// pack mask to bits (streaming kernel), inhale 4KB/block into LDS, prefetch K/Vt.

typedef __bf16 bf16x8 __attribute__((ext_vector_type(8)));
typedef __bf16 bf16x4 __attribute__((ext_vector_type(4)));
typedef float f32x4 __attribute__((ext_vector_type(4)));

#define NB 8
#define LL 2048
#define SS 2048
#define DD 64
#define WORDS (SS / 32)  // 64 u32 bitmask words per row

// ---- prep 0: pack int32 mask -> bitmask (1 bit per element) ----
// wave reads 64 consecutive ints (coalesced), __ballot -> u64, lane0 writes.
__global__ __launch_bounds__(256) void pack_mask(const int* __restrict__ mask,
                                                 unsigned long long* __restrict__ bm) {
  const int w = threadIdx.x >> 6, lane = threadIdx.x & 63;
  const size_t gw = (size_t)blockIdx.x * 4 + w;   // global wave id
  const size_t stride = (size_t)gridDim.x * 4;    // total waves
#pragma unroll
  for (int i = 0; i < 4; ++i) {
    size_t seg = gw + (size_t)i * stride;         // 64-element segment index
    int m = __builtin_nontemporal_load(mask + seg * 64 + lane);
    unsigned long long b = __ballot(m != 0);
    if (lane == 0) bm[seg] = b;
  }
}

// ---- prep 1: L2-normalize Q (fold 1/8) and K rows, cast to bf16 ----
__global__ __launch_bounds__(256) void prep_norm(const float* __restrict__ q,
                                                 const float* __restrict__ k,
                                                 __bf16* __restrict__ Qb,
                                                 __bf16* __restrict__ Kb) {
  int w = threadIdx.x >> 6, lane = threadIdx.x & 63;
  int r = blockIdx.x * 4 + w;
  const float* src;
  __bf16* dst;
  float extra;
  if (r < NB * LL) {
    src = q + (size_t)r * DD;
    dst = Qb + (size_t)r * DD;
    extra = 0.125f;  // fold 1/sqrt(64) into Q
  } else {
    int rk = r - NB * LL;
    src = k + (size_t)rk * DD;
    dst = Kb + (size_t)rk * DD;
    extra = 1.0f;
  }
  float x = src[lane];
  float ss = x * x;
  ss += __shfl_xor(ss, 1);
  ss += __shfl_xor(ss, 2);
  ss += __shfl_xor(ss, 4);
  ss += __shfl_xor(ss, 8);
  ss += __shfl_xor(ss, 16);
  ss += __shfl_xor(ss, 32);
  float nrm = sqrtf(ss);
  float sc = extra / fmaxf(nrm, 1e-12f);
  dst[lane] = (__bf16)(x * sc);
}

// ---- prep 2: V [n][s][v] f32 -> Vt [n][v][s] bf16 (64x64 LDS tiles) ----
__global__ __launch_bounds__(256) void prep_vt(const float* __restrict__ v,
                                               __bf16* __restrict__ Vt) {
  __shared__ __bf16 tile[64][72];
  int n = blockIdx.y;
  int s0 = blockIdx.x * 64;
  int t = threadIdx.x;
#pragma unroll
  for (int it = 0; it < 4; ++it) {
    int idx = t + it * 256;
    int s = idx >> 4, c = idx & 15;
    float4 f = *(const float4*)(v + ((size_t)(n * SS + s0 + s)) * DD + c * 4);
    tile[s][c * 4 + 0] = (__bf16)f.x;
    tile[s][c * 4 + 1] = (__bf16)f.y;
    tile[s][c * 4 + 2] = (__bf16)f.z;
    tile[s][c * 4 + 3] = (__bf16)f.w;
  }
  __syncthreads();
#pragma unroll
  for (int it = 0; it < 4; ++it) {
    int idx = t + it * 256;
    int vv = idx >> 4, c = idx & 15;
    bf16x4 o;
    o[0] = tile[c * 4 + 0][vv];
    o[1] = tile[c * 4 + 1][vv];
    o[2] = tile[c * 4 + 2][vv];
    o[3] = tile[c * 4 + 3][vv];
    *(bf16x4*)(Vt + ((size_t)(n * DD + vv)) * SS + s0 + c * 4) = o;
  }
}

// ---- main: 16 L-rows per block, 4 waves, stream S in 64-col chunks ----
__global__ __launch_bounds__(256, 4) void attn_main(const __bf16* __restrict__ Qb,
                                                    const __bf16* __restrict__ Kb,
                                                    const __bf16* __restrict__ Vt,
                                                    const unsigned* __restrict__ bm32,
                                                    float* __restrict__ out_val,
                                                    float* __restrict__ out_score) {
  __shared__ __bf16 e_lds[2][16][72];   // exp-score chunk, C/D->A layout bounce
  __shared__ float rs_lds[4][16];       // per-wave row-sum partials
  __shared__ unsigned bm_t[WORDS][16];  // bitmask, [word][row]: rows contiguous

  const int n = blockIdx.y;
  const int l0 = blockIdx.x * 16;
  const int t = threadIdx.x;
  const int w = t >> 6;
  const int lane = t & 63;
  const int m16 = lane & 15;   // MFMA A row / B col / C col
  const int quad = lane >> 4;  // C/D row group

  // --- inhale this block's bitmask: 16 rows x 64 words = 4KB ---
  {
    int word = t & 63, wv = t >> 6;
#pragma unroll
    for (int i = 0; i < 4; ++i) {
      int row = wv * 4 + i;
      bm_t[word][row] = bm32[(((size_t)(n * LL + l0 + row)) << 6) + word];
    }
  }

  // Q A-frags: A[m=lane&15][k=quad*8+j], two k-steps of 32
  const __bf16* qrow = Qb + ((size_t)(n * LL + l0 + m16)) * DD;
  bf16x8 aq0 = *(const bf16x8*)(qrow + quad * 8);
  bf16x8 aq1 = *(const bf16x8*)(qrow + 32 + quad * 8);

  const __bf16* kbase = Kb + (size_t)n * SS * DD;
  const __bf16* vbase = Vt + (size_t)n * DD * SS + (size_t)(16 * w + m16) * SS;
  const size_t mrow_base = ((size_t)(n * LL + l0)) * SS;
  const int scol_off = w * 16 + m16;  // s-col offset within a chunk
  const unsigned shift = (unsigned)(scol_off & 31);
  const int word_off = scol_off >> 5;  // 0 or 1

  f32x4 acc_o = {0.f, 0.f, 0.f, 0.f};
  float rsum[4] = {0.f, 0.f, 0.f, 0.f};

  // --- preload chunk 0 K + Vt fragments ---
  const __bf16* krow0 = kbase + (size_t)scol_off * DD;
  bf16x8 kb0 = *(const bf16x8*)(krow0 + quad * 8);
  bf16x8 kb1 = *(const bf16x8*)(krow0 + 32 + quad * 8);
  bf16x8 vb0 = *(const bf16x8*)(vbase + quad * 8);
  bf16x8 vb1 = *(const bf16x8*)(vbase + 32 + quad * 8);

  __syncthreads();  // bm_t ready

  for (int c = 0; c < SS / 64; ++c) {
    // --- prefetch chunk c+1 (wrapped; last iter loads chunk 0 harmlessly) ---
    const int cn = (c + 1) & 31;
    const __bf16* krow_n = kbase + (size_t)(cn * 64 + scol_off) * DD;
    bf16x8 nkb0 = *(const bf16x8*)(krow_n + quad * 8);
    bf16x8 nkb1 = *(const bf16x8*)(krow_n + 32 + quad * 8);
    bf16x8 nvb0 = *(const bf16x8*)(vbase + cn * 64 + quad * 8);
    bf16x8 nvb1 = *(const bf16x8*)(vbase + cn * 64 + 32 + quad * 8);

    // --- QK^T for this wave's 16 s-cols ---
    f32x4 acc = {0.f, 0.f, 0.f, 0.f};
    acc = __builtin_amdgcn_mfma_f32_16x16x32_bf16(aq0, kb0, acc, 0, 0, 0);
    acc = __builtin_amdgcn_mfma_f32_16x16x32_bf16(aq1, kb1, acc, 0, 0, 0);

    // --- mask bits (LDS), exp, rowsum, stash bf16 e (C/D layout rows) ---
    const uint4 mw = *(const uint4*)&bm_t[c * 2 + word_off][quad * 4];
#pragma unroll
    for (int r = 0; r < 4; ++r) {
      unsigned mk = ((&mw.x)[r] >> shift) & 1u;
      float e = mk ? __expf(acc[r]) : 0.0f;
      rsum[r] += e;
      e_lds[c & 1][quad * 4 + r][w * 16 + m16] = (__bf16)e;
    }
    __syncthreads();

    // --- PV: acc_o += E_chunk @ V_chunk ---
    bf16x8 ae0 = *(const bf16x8*)(&e_lds[c & 1][m16][quad * 8]);
    bf16x8 ae1 = *(const bf16x8*)(&e_lds[c & 1][m16][32 + quad * 8]);
    acc_o = __builtin_amdgcn_mfma_f32_16x16x32_bf16(ae0, vb0, acc_o, 0, 0, 0);
    acc_o = __builtin_amdgcn_mfma_f32_16x16x32_bf16(ae1, vb1, acc_o, 0, 0, 0);
    // dbuf proof: e_lds[c&1] next written at c+2, after barrier c+1, after reads at c.

    kb0 = nkb0; kb1 = nkb1; vb0 = nvb0; vb1 = nvb1;
  }

  // --- rowsum reduce: 16 lanes via shfl, then 4 waves via LDS ---
#pragma unroll
  for (int r = 0; r < 4; ++r) {
    float s = rsum[r];
    s += __shfl_xor(s, 1);
    s += __shfl_xor(s, 2);
    s += __shfl_xor(s, 4);
    s += __shfl_xor(s, 8);
    rsum[r] = s;
  }
  if (m16 == 0) {
#pragma unroll
    for (int r = 0; r < 4; ++r) rs_lds[w][quad * 4 + r] = rsum[r];
  }
  __syncthreads();
  float inv[4];
#pragma unroll
  for (int r = 0; r < 4; ++r) {
    int row = quad * 4 + r;
    float s = rs_lds[0][row] + rs_lds[1][row] + rs_lds[2][row] + rs_lds[3][row];
    inv[r] = 1.0f / s;
  }

  // --- out_value = acc_o * inv (C/D layout: row=quad*4+r, col=16w+m16) ---
#pragma unroll
  for (int r = 0; r < 4; ++r) {
    int row = quad * 4 + r;
    out_val[((size_t)(n * LL + l0 + row)) * DD + 16 * w + m16] = acc_o[r] * inv[r];
  }

  // --- pass B: recompute scores, normalize, store P (the big HBM write) ---
  bf16x8 pk0 = *(const bf16x8*)(krow0 + quad * 8);
  bf16x8 pk1 = *(const bf16x8*)(krow0 + 32 + quad * 8);
  for (int c = 0; c < SS / 64; ++c) {
    const int cn = (c + 1) & 31;
    const __bf16* krow_n = kbase + (size_t)(cn * 64 + scol_off) * DD;
    bf16x8 nk0 = *(const bf16x8*)(krow_n + quad * 8);
    bf16x8 nk1 = *(const bf16x8*)(krow_n + 32 + quad * 8);

    f32x4 acc = {0.f, 0.f, 0.f, 0.f};
    acc = __builtin_amdgcn_mfma_f32_16x16x32_bf16(aq0, pk0, acc, 0, 0, 0);
    acc = __builtin_amdgcn_mfma_f32_16x16x32_bf16(aq1, pk1, acc, 0, 0, 0);

    const uint4 mw = *(const uint4*)&bm_t[c * 2 + word_off][quad * 4];
    const int scol = c * 64 + scol_off;
#pragma unroll
    for (int r = 0; r < 4; ++r) {
      unsigned mk = ((&mw.x)[r] >> shift) & 1u;
      float val = mk ? __expf(acc[r]) * inv[r] : 0.0f;
      size_t idx = mrow_base + (size_t)(quad * 4 + r) * SS + scol;
      __builtin_nontemporal_store(val, out_score + idx);
    }
    pk0 = nk0; pk1 = nk1;
  }
}

extern "C" void kernel_launch(void* const* d_in, const int* in_sizes, int n_in,
                              void* d_out, int out_size, void* d_ws, size_t ws_size,
                              hipStream_t stream) {
  const float* q = (const float*)d_in[0];
  const float* k = (const float*)d_in[1];
  const float* v = (const float*)d_in[2];
  const int* mask = (const int*)d_in[3];  // bool materialized as int32

  float* out_val = (float*)d_out;                     // [8,2048,64]
  float* out_score = out_val + (size_t)NB * LL * DD;  // [8,2048,2048]

  __bf16* Qb = (__bf16*)d_ws;                              // 2 MB
  __bf16* Kb = Qb + (size_t)NB * LL * DD;                  // 2 MB
  __bf16* Vt = Kb + (size_t)NB * SS * DD;                  // 2 MB
  unsigned long long* bm = (unsigned long long*)(Vt + (size_t)NB * DD * SS);  // 4 MB

  pack_mask<<<dim3(32768), dim3(256), 0, stream>>>(mask, bm);
  prep_norm<<<dim3((NB * LL * 2) / 4), dim3(256), 0, stream>>>(q, k, Qb, Kb);
  prep_vt<<<dim3(SS / 64, NB), dim3(256), 0, stream>>>(v, Vt);
  attn_main<<<dim3(LL / 16, NB), dim3(256), 0, stream>>>(Qb, Kb, Vt, (const unsigned*)bm,
                                                         out_val, out_score);
}